// Round 3
// baseline (2998.479 us; speedup 1.0000x reference)
//
#include <hip/hip_runtime.h>
#include <math.h>

typedef __bf16 bf16x8 __attribute__((ext_vector_type(8)));
typedef float f32x4 __attribute__((ext_vector_type(4)));
typedef unsigned short ushort_t;

#define SEQ 2048
#define MROWS 4096          // B*S
#define EPS 1e-5f

// ---------- bf16 helpers ----------
__device__ __forceinline__ float bf2f(ushort_t u) {
  union { unsigned int i; float f; } c; c.i = ((unsigned int)u) << 16; return c.f;
}
__device__ __forceinline__ ushort_t f2bf(float f) {
  union { unsigned int i; float f; } c; c.f = f;
  unsigned int i = c.i;
  unsigned int r = i + 0x7fffu + ((i >> 16) & 1u);   // RNE
  return (ushort_t)(r >> 16);
}

// ---------- reductions ----------
__device__ __forceinline__ float wave_sum(float v) {
  #pragma unroll
  for (int off = 32; off > 0; off >>= 1) v += __shfl_xor(v, off);
  return v;
}
__device__ __forceinline__ float wave_max(float v) {
  #pragma unroll
  for (int off = 32; off > 0; off >>= 1) v = fmaxf(v, __shfl_xor(v, off));
  return v;
}

// ---------- 0a. dtype detector: is x bf16 (1) or fp32 (0)? ----------
// Looks at bits 14..7 of the LOW 16 bits of each of the first 4096 uint32s.
// bf16 data: that field is an exponent of a ~N(0,1) value -> in [100,150] ~99%.
// fp32 data:那 field is uniform mantissa bits -> in range ~20%.
__global__ void detect_kernel(const unsigned int* __restrict__ xraw, int* __restrict__ flag) {
  int tid = threadIdx.x;
  int cnt = 0;
  for (int i = tid; i < 4096; i += 256) {
    unsigned int e = (xraw[i] >> 7) & 0xFFu;
    cnt += (e >= 100u && e <= 150u) ? 1 : 0;
  }
  __shared__ int sred[256];
  sred[tid] = cnt;
  __syncthreads();
  for (int s = 128; s > 0; s >>= 1) {
    if (tid < s) sred[tid] += sred[tid + s];
    __syncthreads();
  }
  if (tid == 0) flag[0] = (sred[0] > 2048) ? 1 : 0;
}

// ---------- 0b. canonicalize input -> fp32 ----------
__global__ void conv_kernel(const void* __restrict__ in, float* __restrict__ outp,
                            int n, const int* __restrict__ flag) {
  int i = blockIdx.x * 256 + threadIdx.x;
  if (i >= n) return;
  if (*flag) outp[i] = bf2f(((const ushort_t*)in)[i]);
  else       outp[i] = ((const float*)in)[i];
}

// ---------- 1. prenorm RMSNorm (fp32) ----------
__global__ void prenorm_kernel(const float* __restrict__ x,
                               const float* __restrict__ w,
                               float* __restrict__ xn) {
  int row = blockIdx.x;
  int tid = threadIdx.x;
  const float4* xv = (const float4*)(x + (long long)row * 1024);
  float4 u = xv[tid];
  float ss = u.x*u.x + u.y*u.y + u.z*u.z + u.w*u.w;
  ss = wave_sum(ss);
  __shared__ float red[4];
  if ((tid & 63) == 0) red[tid >> 6] = ss;
  __syncthreads();
  float total = red[0] + red[1] + red[2] + red[3];
  float inv = rsqrtf(total * (1.0f / 1024.0f) + EPS);
  float4 wu = ((const float4*)w)[tid];
  float4 o;
  o.x = u.x * inv * wu.x;
  o.y = u.y * inv * wu.y;
  o.z = u.z * inv * wu.z;
  o.w = u.w * inv * wu.w;
  ((float4*)(xn + (long long)row * 1024))[tid] = o;
}

// ---------- 2. fp32 GEMM via in-register bf16 hi/lo split MFMA ----------
// C[m][n] = sum_k A[m][k]*B[n][k]  (+ res).  a = ah+al, b = bh+bl;
// acc += al*bh + ah*bl + ah*bh  (lo*lo dropped, ~2^-16 rel).
__global__ void gemm_bt(const float* __restrict__ A, const float* __restrict__ B,
                        float* __restrict__ C, const float* __restrict__ res,
                        int K, int lda, int ldb, int ldc) {
  int lane = threadIdx.x & 63;
  int wave = threadIdx.x >> 6;
  int m0 = (blockIdx.y * 4 + wave) * 16;
  int n0 = blockIdx.x * 16;
  const float* Ap = A + (long long)(m0 + (lane & 15)) * lda + ((lane >> 4) << 3);
  const float* Bp = B + (long long)(n0 + (lane & 15)) * ldb + ((lane >> 4) << 3);
  f32x4 acc = {0.f, 0.f, 0.f, 0.f};
  for (int k = 0; k < K; k += 32) {
    f32x4 a0 = *(const f32x4*)(Ap + k);
    f32x4 a1 = *(const f32x4*)(Ap + k + 4);
    f32x4 b0 = *(const f32x4*)(Bp + k);
    f32x4 b1 = *(const f32x4*)(Bp + k + 4);
    bf16x8 ah, al, bh, bl;
    #pragma unroll
    for (int j = 0; j < 4; ++j) {
      float a = a0[j]; __bf16 h = (__bf16)a; ah[j] = h; al[j] = (__bf16)(a - (float)h);
      a = a1[j]; h = (__bf16)a; ah[j+4] = h; al[j+4] = (__bf16)(a - (float)h);
      a = b0[j]; h = (__bf16)a; bh[j] = h; bl[j] = (__bf16)(a - (float)h);
      a = b1[j]; h = (__bf16)a; bh[j+4] = h; bl[j+4] = (__bf16)(a - (float)h);
    }
    acc = __builtin_amdgcn_mfma_f32_16x16x32_bf16(al, bh, acc, 0, 0, 0);
    acc = __builtin_amdgcn_mfma_f32_16x16x32_bf16(ah, bl, acc, 0, 0, 0);
    acc = __builtin_amdgcn_mfma_f32_16x16x32_bf16(ah, bh, acc, 0, 0, 0);
  }
  int col = n0 + (lane & 15);
  int row0 = m0 + ((lane >> 4) << 2);
  #pragma unroll
  for (int r = 0; r < 4; ++r) {
    long long idx = (long long)(row0 + r) * ldc + col;
    float v = acc[r];
    if (res) v += res[idx];
    C[idx] = v;
  }
}

// ---------- 3. q/k per-head RMSNorm (fp32, + fold 1/sqrt(64) into q) ----------
__global__ void qk_norm_kernel(float* __restrict__ q, float* __restrict__ k,
                               const float* __restrict__ qw, const float* __restrict__ kw) {
  int wid = blockIdx.x * 4 + (threadIdx.x >> 6);
  int lane = threadIdx.x & 63;
  int head = wid & 15;
  int isk = (wid >> 4) & 1;
  int row = wid >> 5;               // 0..4095
  float* p = (isk ? k : q) + (long long)row * 1024 + head * 64 + lane;
  float v = *p;
  float ss = wave_sum(v * v);
  float inv = rsqrtf(ss * (1.0f / 64.0f) + EPS);
  float w = isk ? kw[lane] : qw[lane];
  float scale = isk ? 1.0f : 0.125f;
  *p = v * inv * w * scale;
}

// ---------- 4. V transpose (fp32): Vt[bh][d][s] = v[b*S+s][h*64+d] ----------
__global__ void vt_kernel(const float* __restrict__ v, float* __restrict__ Vt) {
  __shared__ float tile[64][65];
  int s0 = blockIdx.x * 64;
  int bh = blockIdx.y;
  int b = bh >> 4, h = bh & 15;
  const float* src = v + (long long)b * SEQ * 1024 + h * 64;
  int d = threadIdx.x & 63, srow = threadIdx.x >> 6;
  #pragma unroll
  for (int i = 0; i < 16; ++i) {
    int sl = i * 4 + srow;
    tile[sl][d] = src[(long long)(s0 + sl) * 1024 + d];
  }
  __syncthreads();
  float* dst = Vt + (long long)bh * 64 * SEQ + s0;
  int sl2 = threadIdx.x & 63, drow = threadIdx.x >> 6;
  #pragma unroll
  for (int i = 0; i < 16; ++i) {
    int dd = i * 4 + drow;
    dst[(long long)dd * SEQ + sl2] = tile[sl2][dd];
  }
}

// ---------- 5. row softmax over 2048 cols (fp32, in place) ----------
__global__ void softmax_kernel(float* __restrict__ P) {
  long long base = (long long)blockIdx.x * SEQ;
  int tid = threadIdx.x;
  float4 u0 = ((const float4*)(P + base))[tid * 2];
  float4 u1 = ((const float4*)(P + base))[tid * 2 + 1];
  float v[8] = {u0.x, u0.y, u0.z, u0.w, u1.x, u1.y, u1.z, u1.w};
  float mx = v[0];
  #pragma unroll
  for (int i = 1; i < 8; ++i) mx = fmaxf(mx, v[i]);
  mx = wave_max(mx);
  __shared__ float red[4];
  if ((tid & 63) == 0) red[tid >> 6] = mx;
  __syncthreads();
  mx = fmaxf(fmaxf(red[0], red[1]), fmaxf(red[2], red[3]));
  __syncthreads();
  float s = 0.f;
  #pragma unroll
  for (int i = 0; i < 8; ++i) { v[i] = __expf(v[i] - mx); s += v[i]; }
  s = wave_sum(s);
  if ((tid & 63) == 0) red[tid >> 6] = s;
  __syncthreads();
  s = red[0] + red[1] + red[2] + red[3];
  float inv = 1.0f / s;
  float4 o0 = {v[0]*inv, v[1]*inv, v[2]*inv, v[3]*inv};
  float4 o1 = {v[4]*inv, v[5]*inv, v[6]*inv, v[7]*inv};
  ((float4*)(P + base))[tid * 2]     = o0;
  ((float4*)(P + base))[tid * 2 + 1] = o1;
}

// ---------- 6. multiply attention output by sigmoid(gate) (fp32) ----------
__global__ void gate_mul_kernel(float* __restrict__ ao, const float* __restrict__ gate) {
  int idx4 = blockIdx.x * 256 + threadIdx.x;   // units of 4 contiguous floats
  long long idx = (long long)idx4 * 4;
  int bs = (int)(idx >> 10);
  int h = ((int)(idx) >> 6) & 15;
  float g = gate[bs * 16 + h];
  float sg = 1.0f / (1.0f + __expf(-g));
  float4 u = ((const float4*)ao)[idx4];
  u.x *= sg; u.y *= sg; u.z *= sg; u.w *= sg;
  ((float4*)ao)[idx4] = u;
}

// ---------- 7. output writer: fp32 or bf16 per flag ----------
__global__ void out_write_kernel(const float* __restrict__ tmp, void* __restrict__ out,
                                 const int* __restrict__ flag) {
  int i = blockIdx.x * 256 + threadIdx.x;
  if (i >= 4194304) return;
  float v = tmp[i];
  if (*flag) ((ushort_t*)out)[i] = f2bf(v);
  else       ((float*)out)[i] = v;
}

extern "C" void kernel_launch(void* const* d_in, const int* in_sizes, int n_in,
                              void* d_out, int out_size, void* d_ws, size_t ws_size,
                              hipStream_t stream) {
  (void)in_sizes; (void)n_in; (void)out_size; (void)ws_size;
  char* ws = (char*)d_ws;
  // canonical fp32 inputs
  float* cx   = (float*)(ws);                         // 16 MB  4096x1024
  float* cqw  = (float*)(ws + (16ll << 20));          // 12 MB  3072x1024
  float* cow  = (float*)(ws + (28ll << 20));          //  4 MB  1024x1024
  float* cpw  = (float*)(ws + (32ll << 20));          //  4 KB
  float* cqn  = (float*)(ws + (32ll << 20) + 8192);   // 256 B
  float* ckn  = (float*)(ws + (32ll << 20) + 16384);  // 256 B
  float* cgw  = (float*)(ws + (32ll << 20) + 32768);  // 64 KB  16x1024
  int*   flag = (int*)  (ws + (32ll << 20) + 131072);
  float* gate = (float*)(ws + (32ll << 20) + 262144); // 256 KB 4096x16
  // pipeline buffers
  float* xn  = (float*)(ws + (33ll << 20));           // 16 MB (phase1) -> P (loop) -> tmp (final)
  float* P   = xn;
  float* tmp = xn;
  float* q   = (float*)(ws + (49ll << 20));           // 16 MB
  float* k   = (float*)(ws + (65ll << 20));           // 16 MB
  float* v   = (float*)(ws + (81ll << 20));           // 16 MB (dead after vt) -> ao
  float* ao  = v;
  float* Vt  = (float*)(ws + (97ll << 20));           // 16 MB   (peak 113 MB)

  // 0. detect dtype, canonicalize inputs
  detect_kernel<<<1, 256, 0, stream>>>((const unsigned int*)d_in[0], flag);
  conv_kernel<<<16384, 256, 0, stream>>>(d_in[0], cx, 4194304, flag);
  conv_kernel<<<4, 256, 0, stream>>>(d_in[1], cpw, 1024, flag);
  conv_kernel<<<12288, 256, 0, stream>>>(d_in[2], cqw, 3145728, flag);
  conv_kernel<<<64, 256, 0, stream>>>(d_in[3], cgw, 16384, flag);
  conv_kernel<<<4096, 256, 0, stream>>>(d_in[4], cow, 1048576, flag);
  conv_kernel<<<1, 256, 0, stream>>>(d_in[5], cqn, 64, flag);
  conv_kernel<<<1, 256, 0, stream>>>(d_in[6], ckn, 64, flag);

  // 1. prenorm
  prenorm_kernel<<<MROWS, 256, 0, stream>>>(cx, cpw, xn);
  // 2. q/k/v/gate projections (B rows of qkv_w: q=0..1023, k=1024.., v=2048..)
  gemm_bt<<<dim3(64, 64), 256, 0, stream>>>(xn, cqw,                q, nullptr, 1024, 1024, 1024, 1024);
  gemm_bt<<<dim3(64, 64), 256, 0, stream>>>(xn, cqw + 1024 * 1024,  k, nullptr, 1024, 1024, 1024, 1024);
  gemm_bt<<<dim3(64, 64), 256, 0, stream>>>(xn, cqw + 2048 * 1024,  v, nullptr, 1024, 1024, 1024, 1024);
  gemm_bt<<<dim3(1, 64),  256, 0, stream>>>(xn, cgw, gate, nullptr, 1024, 1024, 1024, 16);
  // 3. q/k RMSNorm (+ q *= 0.125)
  qk_norm_kernel<<<32768, 256, 0, stream>>>(q, k, cqn, ckn);
  // 4. V transpose
  vt_kernel<<<dim3(32, 32), 256, 0, stream>>>(v, Vt);
  // 5. attention, one (b,h) at a time (xn dead; P reuses its slot)
  for (int bh = 0; bh < 32; ++bh) {
    int b = bh >> 4, h = bh & 15;
    const float* Aq = q + (long long)b * SEQ * 1024 + h * 64;
    const float* Bk = k + (long long)b * SEQ * 1024 + h * 64;
    gemm_bt<<<dim3(128, 32), 256, 0, stream>>>(Aq, Bk, P, nullptr, 64, 1024, 1024, SEQ);
    softmax_kernel<<<SEQ, 256, 0, stream>>>(P);
    const float* Bv = Vt + (long long)bh * 64 * SEQ;
    float* Co = ao + (long long)b * SEQ * 1024 + h * 64;
    gemm_bt<<<dim3(4, 32), 256, 0, stream>>>(P, Bv, Co, nullptr, SEQ, SEQ, SEQ, 1024);
  }
  // 6. gate
  gate_mul_kernel<<<4096, 256, 0, stream>>>(ao, gate);
  // 7. out = ao @ o_w^T + x  -> tmp (fp32), then dtype-dispatched write
  gemm_bt<<<dim3(64, 64), 256, 0, stream>>>(ao, cow, tmp, cx, 1024, 1024, 1024, 1024);
  out_write_kernel<<<16384, 256, 0, stream>>>(tmp, d_out, flag);
}

// Round 4
// 366.283 us; speedup vs baseline: 8.1862x; 8.1862x over previous
//
#include <hip/hip_runtime.h>
#include <math.h>

typedef __bf16 bf16x8 __attribute__((ext_vector_type(8)));
typedef float f32x4 __attribute__((ext_vector_type(4)));
typedef unsigned short ushort_t;

#define SEQ 2048
#define MROWS 4096          // B*S
#define EPS 1e-5f

// ---------- bf16 helpers ----------
__device__ __forceinline__ float bf2f(ushort_t u) {
  union { unsigned int i; float f; } c; c.i = ((unsigned int)u) << 16; return c.f;
}
__device__ __forceinline__ ushort_t f2bf(float f) {
  union { unsigned int i; float f; } c; c.f = f;
  unsigned int i = c.i;
  unsigned int r = i + 0x7fffu + ((i >> 16) & 1u);   // RNE
  return (ushort_t)(r >> 16);
}

// async global->LDS, 16B per lane; lds dest must be wave-uniform base
__device__ __forceinline__ void gll16(const ushort_t* g, ushort_t* l) {
  __builtin_amdgcn_global_load_lds(
      (const __attribute__((address_space(1))) unsigned int*)g,
      (__attribute__((address_space(3))) unsigned int*)l, 16, 0, 0);
}

// ---------- reductions ----------
__device__ __forceinline__ float wave_sum(float v) {
  #pragma unroll
  for (int off = 32; off > 0; off >>= 1) v += __shfl_xor(v, off);
  return v;
}

// ---------- 0a. dtype detector: is x bf16 (1) or fp32 (0)? ----------
__global__ void detect_kernel(const unsigned int* __restrict__ xraw, int* __restrict__ flag) {
  int tid = threadIdx.x;
  int cnt = 0;
  for (int i = tid; i < 4096; i += 256) {
    unsigned int e = (xraw[i] >> 7) & 0xFFu;
    cnt += (e >= 100u && e <= 150u) ? 1 : 0;
  }
  __shared__ int sred[256];
  sred[tid] = cnt;
  __syncthreads();
  for (int s = 128; s > 0; s >>= 1) {
    if (tid < s) sred[tid] += sred[tid + s];
    __syncthreads();
  }
  if (tid == 0) flag[0] = (sred[0] > 2048) ? 1 : 0;
}

// ---------- 0b. canonicalize ----------
__global__ void conv_f32(const void* __restrict__ in, float* __restrict__ outp,
                         int n, const int* __restrict__ flag) {
  int i = blockIdx.x * 256 + threadIdx.x;
  if (i >= n) return;
  if (*flag) outp[i] = bf2f(((const ushort_t*)in)[i]);
  else       outp[i] = ((const float*)in)[i];
}
__global__ void conv_b16(const void* __restrict__ in, ushort_t* __restrict__ outp,
                         int n, const int* __restrict__ flag) {
  int i = blockIdx.x * 256 + threadIdx.x;
  if (i >= n) return;
  if (*flag) outp[i] = ((const ushort_t*)in)[i];
  else       outp[i] = f2bf(((const float*)in)[i]);
}

// ---------- 1. prenorm RMSNorm (fp32 in, bf16 out) ----------
__global__ void prenorm_kernel(const float* __restrict__ x,
                               const float* __restrict__ w,
                               ushort_t* __restrict__ xn) {
  int row = blockIdx.x;
  int tid = threadIdx.x;
  float4 u = ((const float4*)(x + (long long)row * 1024))[tid];
  float ss = u.x*u.x + u.y*u.y + u.z*u.z + u.w*u.w;
  ss = wave_sum(ss);
  __shared__ float red[4];
  if ((tid & 63) == 0) red[tid >> 6] = ss;
  __syncthreads();
  float total = red[0] + red[1] + red[2] + red[3];
  float inv = rsqrtf(total * (1.0f / 1024.0f) + EPS);
  float4 wu = ((const float4*)w)[tid];
  ushort4 o;
  o.x = f2bf(u.x * inv * wu.x);
  o.y = f2bf(u.y * inv * wu.y);
  o.z = f2bf(u.z * inv * wu.z);
  o.w = f2bf(u.w * inv * wu.w);
  ((ushort4*)(xn + (long long)row * 1024))[tid] = o;
}

// ---------- 2. tiled bf16 GEMM (m97 structure): C[m][n]=sum_k A[m][k]B[n][k] ----------
// 128x128 tile, 4 waves 2x2 (64x64 each), BK=32, global_load_lds staging.
__global__ void gemm_tiled(const ushort_t* __restrict__ A, const ushort_t* __restrict__ B,
                           void* __restrict__ Cv, const float* __restrict__ res,
                           const int* __restrict__ flag,
                           int K, int lda, int ldb, int ldc) {
  __shared__ ushort_t As[128 * 32];
  __shared__ ushort_t Bs[128 * 32];
  int tid = threadIdx.x, wave = tid >> 6, lane = tid & 63;
  int m_blk = blockIdx.y * 128, n_blk = blockIdx.x * 128;
  int wm = (wave & 1) * 64, wn = (wave >> 1) * 64;
  int g = lane >> 4, c = lane & 15;
  int arow = lane >> 2;            // 0..15 within a 16-row wave chunk
  int akc = (lane & 3) << 3;       // 0,8,16,24
  f32x4 acc[4][4] = {};
  for (int kt = 0; kt < K; kt += 32) {
    #pragma unroll
    for (int i = 0; i < 2; ++i) {
      int rbase = (i * 4 + wave) * 16;
      gll16(A + (long long)(m_blk + rbase + arow) * lda + kt + akc, &As[rbase * 32]);
      gll16(B + (long long)(n_blk + rbase + arow) * ldb + kt + akc, &Bs[rbase * 32]);
    }
    __syncthreads();
    bf16x8 af[4], bfr[4];
    #pragma unroll
    for (int mi = 0; mi < 4; ++mi)
      af[mi] = *(const bf16x8*)&As[(wm + mi * 16 + c) * 32 + (g << 3)];
    #pragma unroll
    for (int ni = 0; ni < 4; ++ni)
      bfr[ni] = *(const bf16x8*)&Bs[(wn + ni * 16 + c) * 32 + (g << 3)];
    #pragma unroll
    for (int mi = 0; mi < 4; ++mi)
      #pragma unroll
      for (int ni = 0; ni < 4; ++ni)
        acc[mi][ni] = __builtin_amdgcn_mfma_f32_16x16x32_bf16(af[mi], bfr[ni], acc[mi][ni], 0, 0, 0);
    __syncthreads();
  }
  int outbf = flag ? *flag : 1;
  #pragma unroll
  for (int mi = 0; mi < 4; ++mi)
    #pragma unroll
    for (int ni = 0; ni < 4; ++ni)
      #pragma unroll
      for (int r = 0; r < 4; ++r) {
        int row = m_blk + wm + mi * 16 + g * 4 + r;
        int col = n_blk + wn + ni * 16 + c;
        long long idx = (long long)row * ldc + col;
        float v = acc[mi][ni][r];
        if (res) v += res[idx];
        if (outbf) ((ushort_t*)Cv)[idx] = f2bf(v);
        else       ((float*)Cv)[idx] = v;
      }
}

// ---------- 2b. small wave GEMM for gate (bf16 in, fp32 out), N=16 ----------
__global__ void gate_gemm(const ushort_t* __restrict__ A, const ushort_t* __restrict__ B,
                          float* __restrict__ C) {
  int lane = threadIdx.x & 63;
  int wave = threadIdx.x >> 6;
  int m0 = (blockIdx.y * 4 + wave) * 16;
  const ushort_t* Ap = A + (long long)(m0 + (lane & 15)) * 1024 + ((lane >> 4) << 3);
  const ushort_t* Bp = B + (long long)(lane & 15) * 1024 + ((lane >> 4) << 3);
  f32x4 acc = {0.f, 0.f, 0.f, 0.f};
  for (int k = 0; k < 1024; k += 32) {
    bf16x8 a = *(const bf16x8*)(Ap + k);
    bf16x8 b = *(const bf16x8*)(Bp + k);
    acc = __builtin_amdgcn_mfma_f32_16x16x32_bf16(a, b, acc, 0, 0, 0);
  }
  int col = lane & 15;
  int row0 = m0 + ((lane >> 4) << 2);
  #pragma unroll
  for (int r = 0; r < 4; ++r) C[(long long)(row0 + r) * 16 + col] = acc[r];
}

// ---------- 3. q/k per-head RMSNorm on packed qkv (bf16), q *= 0.125 ----------
__global__ void qk_norm_kernel(ushort_t* __restrict__ qkv,
                               const float* __restrict__ qw, const float* __restrict__ kw) {
  int wid = blockIdx.x * 4 + (threadIdx.x >> 6);
  int lane = threadIdx.x & 63;
  int head = wid & 15;
  int isk = (wid >> 4) & 1;
  int row = wid >> 5;               // 0..4095
  ushort_t* p = qkv + (long long)row * 3072 + isk * 1024 + head * 64 + lane;
  float v = bf2f(*p);
  float ss = wave_sum(v * v);
  float inv = rsqrtf(ss * (1.0f / 64.0f) + EPS);
  float w = isk ? kw[lane] : qw[lane];
  float scale = isk ? 1.0f : 0.125f;
  *p = f2bf(v * inv * w * scale);
}

// ---------- 4. V transpose (bf16): Vt[bh][d][s] = qkv[b][s][2048+h*64+d] ----------
__global__ void vt_kernel(const ushort_t* __restrict__ qkv, ushort_t* __restrict__ Vt) {
  __shared__ ushort_t tile[64][65];
  int s0 = blockIdx.x * 64;
  int bh = blockIdx.y;
  int b = bh >> 4, h = bh & 15;
  const ushort_t* src = qkv + (long long)b * SEQ * 3072 + 2048 + h * 64;
  int d = threadIdx.x & 63, srow = threadIdx.x >> 6;
  #pragma unroll
  for (int i = 0; i < 16; ++i) {
    int sl = i * 4 + srow;
    tile[sl][d] = src[(long long)(s0 + sl) * 3072 + d];
  }
  __syncthreads();
  ushort_t* dst = Vt + (long long)bh * 64 * SEQ + s0;
  int sl2 = threadIdx.x & 63, drow = threadIdx.x >> 6;
  #pragma unroll
  for (int i = 0; i < 16; ++i) {
    int dd = i * 4 + drow;
    dst[(long long)dd * SEQ + sl2] = tile[sl2][dd];
  }
}

// ---------- 5. flash attention: one block = 64 q-rows of one (b,h) ----------
// grid (SEQ/64, 32). Q-tile 64 (16 rows/wave), KV-tile 64, online softmax.
__global__ void flash_kernel(const ushort_t* __restrict__ qkv, const ushort_t* __restrict__ Vt,
                             ushort_t* __restrict__ ao) {
  __shared__ ushort_t Ks[64 * 64];
  __shared__ ushort_t Vs[64 * 64];
  __shared__ ushort_t Ps[4][16 * 64];
  int tid = threadIdx.x, wave = tid >> 6, lane = tid & 63;
  int g = lane >> 4, c = lane & 15;
  int q0 = blockIdx.x * 64;
  int bh = blockIdx.y, b = bh >> 4, h = bh & 15;
  const ushort_t* qbase = qkv + (long long)b * SEQ * 3072 + h * 64;
  const ushort_t* kbase = qbase + 1024;
  const ushort_t* vtbase = Vt + (long long)bh * 64 * SEQ;
  // this wave's q fragments (A-layout: m=c, k=g*8+j (+32))
  int qrow = q0 + wave * 16 + c;
  bf16x8 qa0 = *(const bf16x8*)(qbase + (long long)qrow * 3072 + (g << 3));
  bf16x8 qa1 = *(const bf16x8*)(qbase + (long long)qrow * 3072 + 32 + (g << 3));
  f32x4 accO[4] = {};
  float m_i[4] = {-1e30f, -1e30f, -1e30f, -1e30f};
  float l_i[4] = {0.f, 0.f, 0.f, 0.f};
  int srow = lane >> 3, scol = (lane & 7) << 3;   // staging coords
  for (int s0 = 0; s0 < SEQ; s0 += 64) {
    #pragma unroll
    for (int i = 0; i < 2; ++i) {
      int rb = i * 32 + wave * 8;
      gll16(kbase + (long long)(s0 + rb + srow) * 3072 + scol, &Ks[rb * 64]);
      gll16(vtbase + (long long)(rb + srow) * SEQ + s0 + scol, &Vs[rb * 64]);
    }
    __syncthreads();
    // S = q . k^T  (C-layout: col = n-tile*16 + c, rows g*4+r)
    f32x4 sacc[4] = {};
    #pragma unroll
    for (int ni = 0; ni < 4; ++ni) {
      bf16x8 kb0 = *(const bf16x8*)&Ks[(ni * 16 + c) * 64 + (g << 3)];
      bf16x8 kb1 = *(const bf16x8*)&Ks[(ni * 16 + c) * 64 + 32 + (g << 3)];
      sacc[ni] = __builtin_amdgcn_mfma_f32_16x16x32_bf16(qa0, kb0, sacc[ni], 0, 0, 0);
      sacc[ni] = __builtin_amdgcn_mfma_f32_16x16x32_bf16(qa1, kb1, sacc[ni], 0, 0, 0);
    }
    // online softmax per row r (global wave-row g*4+r), reduce across 16 lanes
    float p[4][4], alpha[4];
    #pragma unroll
    for (int r = 0; r < 4; ++r) {
      float mx = fmaxf(fmaxf(sacc[0][r], sacc[1][r]), fmaxf(sacc[2][r], sacc[3][r]));
      #pragma unroll
      for (int off = 8; off > 0; off >>= 1) mx = fmaxf(mx, __shfl_xor(mx, off));
      float mn = fmaxf(m_i[r], mx);
      alpha[r] = __expf(m_i[r] - mn);
      m_i[r] = mn;
      float rs = 0.f;
      #pragma unroll
      for (int ni = 0; ni < 4; ++ni) { p[ni][r] = __expf(sacc[ni][r] - mn); rs += p[ni][r]; }
      #pragma unroll
      for (int off = 8; off > 0; off >>= 1) rs += __shfl_xor(rs, off);
      l_i[r] = l_i[r] * alpha[r] + rs;
    }
    // P (C-layout) -> LDS -> A-layout; rescale O
    #pragma unroll
    for (int ni = 0; ni < 4; ++ni)
      #pragma unroll
      for (int r = 0; r < 4; ++r)
        Ps[wave][(g * 4 + r) * 64 + ni * 16 + c] = f2bf(p[ni][r]);
    #pragma unroll
    for (int di = 0; di < 4; ++di)
      #pragma unroll
      for (int r = 0; r < 4; ++r) accO[di][r] *= alpha[r];
    bf16x8 pa0 = *(const bf16x8*)&Ps[wave][c * 64 + (g << 3)];
    bf16x8 pa1 = *(const bf16x8*)&Ps[wave][c * 64 + 32 + (g << 3)];
    #pragma unroll
    for (int di = 0; di < 4; ++di) {
      bf16x8 vb0 = *(const bf16x8*)&Vs[(di * 16 + c) * 64 + (g << 3)];
      bf16x8 vb1 = *(const bf16x8*)&Vs[(di * 16 + c) * 64 + 32 + (g << 3)];
      accO[di] = __builtin_amdgcn_mfma_f32_16x16x32_bf16(pa0, vb0, accO[di], 0, 0, 0);
      accO[di] = __builtin_amdgcn_mfma_f32_16x16x32_bf16(pa1, vb1, accO[di], 0, 0, 0);
    }
    __syncthreads();
  }
  // epilogue: O/l -> ao[b][row][h*64+d]
  #pragma unroll
  for (int di = 0; di < 4; ++di)
    #pragma unroll
    for (int r = 0; r < 4; ++r) {
      int row = q0 + wave * 16 + g * 4 + r;
      int col = h * 64 + di * 16 + c;
      ao[(long long)(b * SEQ + row) * 1024 + col] = f2bf(accO[di][r] / l_i[r]);
    }
}

// ---------- 6. gated multiply (bf16 ao, fp32 gate) ----------
__global__ void gate_mul_kernel(ushort_t* __restrict__ ao, const float* __restrict__ gate) {
  int idx4 = blockIdx.x * 256 + threadIdx.x;
  long long idx = (long long)idx4 * 4;
  int bs = (int)(idx >> 10);
  int h = ((int)idx >> 6) & 15;
  float gv = gate[bs * 16 + h];
  float sg = 1.0f / (1.0f + __expf(-gv));
  ushort4 u = ((const ushort4*)ao)[idx4];
  ushort4 o;
  o.x = f2bf(bf2f(u.x) * sg);
  o.y = f2bf(bf2f(u.y) * sg);
  o.z = f2bf(bf2f(u.z) * sg);
  o.w = f2bf(bf2f(u.w) * sg);
  ((ushort4*)ao)[idx4] = o;
}

extern "C" void kernel_launch(void* const* d_in, const int* in_sizes, int n_in,
                              void* d_out, int out_size, void* d_ws, size_t ws_size,
                              hipStream_t stream) {
  (void)in_sizes; (void)n_in; (void)out_size; (void)ws_size;
  char* ws = (char*)d_ws;
  // layout (~73 MB total; round-3 proved >=113 MB available)
  float*    cx    = (float*)   (ws);                          // 16 MB fp32 x (residual + prenorm)
  ushort_t* qkvw  = (ushort_t*)(ws + (16ll << 20));           //  6 MB bf16 3072x1024
  ushort_t* ow    = (ushort_t*)(ws + (22ll << 20));           //  2 MB bf16 1024x1024
  ushort_t* gw    = (ushort_t*)(ws + (24ll << 20));           // 32 KB bf16 16x1024
  float*    pwf   = (float*)   (ws + (24ll << 20) + (64 << 10));
  float*    qnf   = (float*)   (ws + (24ll << 20) + (72 << 10));
  float*    knf   = (float*)   (ws + (24ll << 20) + (76 << 10));
  int*      flag  = (int*)     (ws + (24ll << 20) + (80 << 10));
  float*    gate  = (float*)   (ws + (24ll << 20) + (128 << 10)); // 256 KB fp32 4096x16
  ushort_t* xn    = (ushort_t*)(ws + (25ll << 20));           //  8 MB bf16 4096x1024
  ushort_t* qkv   = (ushort_t*)(ws + (33ll << 20));           // 24 MB bf16 4096x3072
  ushort_t* Vt    = (ushort_t*)(ws + (57ll << 20));           //  8 MB bf16 32x64x2048
  ushort_t* ao    = (ushort_t*)(ws + (65ll << 20));           //  8 MB bf16 4096x1024

  // 0. detect + canonicalize
  detect_kernel<<<1, 256, 0, stream>>>((const unsigned int*)d_in[0], flag);
  conv_f32<<<16384, 256, 0, stream>>>(d_in[0], cx, 4194304, flag);
  conv_f32<<<4, 256, 0, stream>>>(d_in[1], pwf, 1024, flag);
  conv_b16<<<12288, 256, 0, stream>>>(d_in[2], qkvw, 3145728, flag);
  conv_b16<<<64, 256, 0, stream>>>(d_in[3], gw, 16384, flag);
  conv_b16<<<4096, 256, 0, stream>>>(d_in[4], ow, 1048576, flag);
  conv_f32<<<1, 256, 0, stream>>>(d_in[5], qnf, 64, flag);
  conv_f32<<<1, 256, 0, stream>>>(d_in[6], knf, 64, flag);

  // 1. prenorm (fp32 -> bf16)
  prenorm_kernel<<<MROWS, 256, 0, stream>>>(cx, pwf, xn);
  // 2. qkv = xn @ qkv_w^T  (M=4096,N=3072,K=1024), packed ldc=3072
  gemm_tiled<<<dim3(24, 32), 256, 0, stream>>>(xn, qkvw, qkv, nullptr, nullptr,
                                               1024, 1024, 1024, 3072);
  // 2b. gate
  gate_gemm<<<dim3(1, 64), 256, 0, stream>>>(xn, gw, gate);
  // 3. q/k RMSNorm (+ q *= 1/8)
  qk_norm_kernel<<<32768, 256, 0, stream>>>(qkv, qnf, knf);
  // 4. V transpose
  vt_kernel<<<dim3(32, 32), 256, 0, stream>>>(qkv, Vt);
  // 5. flash attention
  flash_kernel<<<dim3(32, 32), 256, 0, stream>>>(qkv, Vt, ao);
  // 6. gate multiply
  gate_mul_kernel<<<4096, 256, 0, stream>>>(ao, gate);
  // 7. out = ao @ o_w^T + x, dtype-dispatched store
  gemm_tiled<<<dim3(8, 32), 256, 0, stream>>>(ao, ow, d_out, cx, flag,
                                              1024, 1024, 1024, 1024);
}